// Round 3
// baseline (168.655 us; speedup 1.0000x reference)
//
#include <hip/hip_runtime.h>

typedef unsigned int u32;
typedef unsigned long long u64;

#define BN_EPS 1e-3f

// ---------------- workspace layout (bytes) ----------------
// bits1: [256][31][31] u32   conv1->pool->bn1->sign
// bits2: [256][14][14] u64   conv2->pool->bn2->sign
// bits3: [256][144]    u64   conv3->bn3->sign (flatten order: word=(h*12+w), bit=ic)
// bitsD: [256]         u64   dense1->bn4->sign
// w2b  : [9][64]  u32        sign bits of w2 over ic (32)
// w3b  : [9][64]  u64        sign bits of w3 over ic (64)
// d1wb : [144][64] u64       sign bits of d1w rows (bit j = row w*64+j), col oc
// d2wb : [10] u64            sign bits of d2w rows
// t1..t4: per-channel sign thresholds  t = mean - beta*sqrt(var+eps)
static const size_t OFF_BITS1 = 0;            // 984064
static const size_t OFF_BITS2 = 984064;       // 401408
static const size_t OFF_BITS3 = 1385472;      // 294912
static const size_t OFF_BITSD = 1680384;      // 2048
static const size_t OFF_W2B   = 1682432;      // 2304
static const size_t OFF_W3B   = 1684736;      // 4608
static const size_t OFF_D1WB  = 1689344;      // 73728
static const size_t OFF_D2WB  = 1763072;      // 128
static const size_t OFF_T1    = 1763200;      // 128
static const size_t OFF_T2    = 1763328;      // 256
static const size_t OFF_T3    = 1763584;      // 256
static const size_t OFF_T4    = 1763840;      // 256
// total ~1.77 MB

// ---------------- prep: pack weights + thresholds ----------------
__global__ __launch_bounds__(256) void k_prep(
    const float* __restrict__ w2, const float* __restrict__ w3,
    const float* __restrict__ d1w, const float* __restrict__ d2w,
    const float* __restrict__ m1, const float* __restrict__ v1, const float* __restrict__ be1,
    const float* __restrict__ m2, const float* __restrict__ v2, const float* __restrict__ be2,
    const float* __restrict__ m3, const float* __restrict__ v3, const float* __restrict__ be3,
    const float* __restrict__ m4, const float* __restrict__ v4, const float* __restrict__ be4,
    u32* __restrict__ w2b, u64* __restrict__ w3b, u64* __restrict__ d1wb,
    u64* __restrict__ d2wb, float* __restrict__ t1, float* __restrict__ t2,
    float* __restrict__ t3, float* __restrict__ t4)
{
    int blk = blockIdx.x, tid = threadIdx.x;
    if (blk < 36) {                       // d1w: 9216 words, [wi][oc]
        int idx = blk * 256 + tid;        // wi = idx>>6, oc = idx&63
        int wi = idx >> 6, oc = idx & 63;
        u64 bits = 0;
        for (int j = 0; j < 64; ++j)
            bits |= (u64)(d1w[(wi * 64 + j) * 64 + oc] >= 0.f) << j;
        d1wb[idx] = bits;
    } else if (blk < 39) {                // w2: 576 words [tap][oc]
        int idx = (blk - 36) * 256 + tid;
        if (idx < 576) {
            int tap = idx >> 6, oc = idx & 63;
            u32 bits = 0;
            for (int ic = 0; ic < 32; ++ic)
                bits |= (u32)(w2[(tap * 32 + ic) * 64 + oc] >= 0.f) << ic;
            w2b[idx] = bits;
        }
    } else if (blk < 42) {                // w3: 576 words [tap][oc]
        int idx = (blk - 39) * 256 + tid;
        if (idx < 576) {
            int tap = idx >> 6, oc = idx & 63;
            u64 bits = 0;
            for (int ic = 0; ic < 64; ++ic)
                bits |= (u64)(w3[(tap * 64 + ic) * 64 + oc] >= 0.f) << ic;
            w3b[idx] = bits;
        }
    } else {                              // thresholds + d2w pack
        if (tid < 32)       t1[tid]      = m1[tid] - be1[tid] * sqrtf(v1[tid] + BN_EPS);
        else if (tid < 96)  { int c = tid - 32;  t2[c] = m2[c] - be2[c] * sqrtf(v2[c] + BN_EPS); }
        else if (tid < 160) { int c = tid - 96;  t3[c] = m3[c] - be3[c] * sqrtf(v3[c] + BN_EPS); }
        else if (tid < 224) { int c = tid - 160; t4[c] = m4[c] - be4[c] * sqrtf(v4[c] + BN_EPS); }
        else if (tid < 234) {
            int oc = tid - 224;           // d2w: [64][10]
            u64 bits = 0;
            for (int j = 0; j < 64; ++j)
                bits |= (u64)(d2w[j * 10 + oc] >= 0.f) << j;
            d2wb[oc] = bits;
        }
    }
}

// ---------------- conv1 (fp32 x sign(w1)) + maxpool + bn1-sign ----------------
// thread = one pooled pixel (b,ph,pw); produces one u32 (32 channels)
__global__ __launch_bounds__(256) void k_conv1(
    const float* __restrict__ inp, const float* __restrict__ w1,
    const float* __restrict__ t1, u32* __restrict__ bits1)
{
    __shared__ float wf[32 * 28];   // [oc][tap], padded 27->28 (float4-aligned rows)
    __shared__ float t1s[32];
    int tid = threadIdx.x;
    for (int i = tid; i < 864; i += 256) {
        int oc = i / 27, tap = i - oc * 27;
        wf[oc * 28 + tap] = (w1[tap * 32 + oc] >= 0.f) ? 1.f : -1.f;
    }
    if (tid < 32) t1s[tid] = t1[tid];
    __syncthreads();

    int gid = blockIdx.x * 256 + tid;        // < 246016 = 256*961
    int b = gid / 961;
    int p = gid - b * 961;
    int ph = p / 31, pw = p - ph * 31;

    // 4x4x3 input patch covering the 2x2 conv positions
    float x[4][4][3];
    const float* base = inp + ((b * 64 + 2 * ph) * 64 + 2 * pw) * 3;
#pragma unroll
    for (int i = 0; i < 4; ++i)
#pragma unroll
        for (int j = 0; j < 4; ++j)
#pragma unroll
            for (int k = 0; k < 3; ++k)
                x[i][j][k] = base[(i * 64 + j) * 3 + k];

    u32 word = 0;
#pragma unroll 1
    for (int oc = 0; oc < 32; ++oc) {
        float wv[28];
        const float4* wq = reinterpret_cast<const float4*>(wf + oc * 28);
#pragma unroll
        for (int q = 0; q < 7; ++q) {
            float4 t = wq[q];
            wv[4 * q] = t.x; wv[4 * q + 1] = t.y; wv[4 * q + 2] = t.z; wv[4 * q + 3] = t.w;
        }
        float s00 = 0.f, s01 = 0.f, s10 = 0.f, s11 = 0.f;
#pragma unroll
        for (int ky = 0; ky < 3; ++ky)
#pragma unroll
            for (int kx = 0; kx < 3; ++kx)
#pragma unroll
                for (int ic = 0; ic < 3; ++ic) {
                    float w = wv[(ky * 3 + kx) * 3 + ic];
                    s00 = fmaf(w, x[ky][kx][ic], s00);
                    s01 = fmaf(w, x[ky][kx + 1][ic], s01);
                    s10 = fmaf(w, x[ky + 1][kx][ic], s10);
                    s11 = fmaf(w, x[ky + 1][kx + 1][ic], s11);
                }
        float m = fmaxf(fmaxf(s00, s01), fmaxf(s10, s11));
        if (m >= t1s[oc]) word |= (1u << oc);
    }
    bits1[gid] = word;
}

// ---------------- conv2 (XNOR) + maxpool + bn2-sign ----------------
// wave = one pooled pixel, lane = oc (64). ballot -> u64 word.
__global__ __launch_bounds__(256) void k_conv2(
    const u32* __restrict__ bits1, const u32* __restrict__ w2b,
    const float* __restrict__ t2, u64* __restrict__ bits2)
{
    int lane = threadIdx.x & 63;
    int wid = blockIdx.x * 4 + (threadIdx.x >> 6);   // < 50176 = 256*196
    int b = wid / 196;
    int p = wid - b * 196;
    int ph = p / 14, pw = p - ph * 14;

    const u32* xb = bits1 + b * 961 + (2 * ph) * 31 + 2 * pw;
    u32 xw[4][4];
#pragma unroll
    for (int i = 0; i < 4; ++i)
#pragma unroll
        for (int j = 0; j < 4; ++j)
            xw[i][j] = xb[i * 31 + j];

    u32 wv[9];
#pragma unroll
    for (int t = 0; t < 9; ++t) wv[t] = w2b[t * 64 + lane];

    int mn = 1 << 30;
#pragma unroll
    for (int dy = 0; dy < 2; ++dy)
#pragma unroll
        for (int dx = 0; dx < 2; ++dx) {
            int s = 0;
#pragma unroll
            for (int ky = 0; ky < 3; ++ky)
#pragma unroll
                for (int kx = 0; kx < 3; ++kx)
                    s += __popc(xw[dy + ky][dx + kx] ^ wv[ky * 3 + kx]);
            mn = min(mn, s);
        }
    float val = (float)(288 - 2 * mn);      // max over pool = min popcount
    u64 word = __ballot(val >= t2[lane]);
    if (lane == 0) bits2[wid] = word;
}

// ---------------- conv3 (XNOR) + bn3-sign ----------------
__global__ __launch_bounds__(256) void k_conv3(
    const u64* __restrict__ bits2, const u64* __restrict__ w3b,
    const float* __restrict__ t3, u64* __restrict__ bits3)
{
    int lane = threadIdx.x & 63;
    int wid = blockIdx.x * 4 + (threadIdx.x >> 6);   // < 36864 = 256*144
    int b = wid / 144;
    int p = wid - b * 144;
    int h = p / 12, w = p - h * 12;

    const u64* xb = bits2 + b * 196 + h * 14 + w;
    u64 xw[9];
#pragma unroll
    for (int ky = 0; ky < 3; ++ky)
#pragma unroll
        for (int kx = 0; kx < 3; ++kx)
            xw[ky * 3 + kx] = xb[ky * 14 + kx];

    int s = 0;
#pragma unroll
    for (int t = 0; t < 9; ++t)
        s += __popcll(xw[t] ^ w3b[t * 64 + lane]);
    float val = (float)(576 - 2 * s);
    u64 word = __ballot(val >= t3[lane]);
    if (lane == 0) bits3[wid] = word;       // word index = h*12+w, bit = ic
}

// ---------------- dense1 (XNOR 9216) + bn4-sign ----------------
__global__ __launch_bounds__(256) void k_dense1(
    const u64* __restrict__ bits3, const u64* __restrict__ d1wb,
    const float* __restrict__ t4, u64* __restrict__ bitsD)
{
    int lane = threadIdx.x & 63;
    int b = blockIdx.x * 4 + (threadIdx.x >> 6);     // 256 waves
    const u64* xb = bits3 + b * 144;
    int s = 0;
#pragma unroll 8
    for (int w = 0; w < 144; ++w)
        s += __popcll(xb[w] ^ d1wb[w * 64 + lane]);
    float val = (float)(9216 - 2 * s);
    u64 word = __ballot(val >= t4[lane]);
    if (lane == 0) bitsD[b] = word;
}

// ---------------- dense2 (XNOR 64) + bn5 + softmax ----------------
__global__ __launch_bounds__(256) void k_dense2(
    const u64* __restrict__ bitsD, const u64* __restrict__ d2wb,
    const float* __restrict__ m5, const float* __restrict__ v5,
    const float* __restrict__ be5, float* __restrict__ out)
{
    int b = threadIdx.x;                  // 256 images, one thread each
    u64 xv = bitsD[b];
    float y[10];
    float mx = -1e30f;
#pragma unroll
    for (int j = 0; j < 10; ++j) {
        int v = 64 - 2 * (int)__popcll(xv ^ d2wb[j]);
        y[j] = ((float)v - m5[j]) * rsqrtf(v5[j] + BN_EPS) + be5[j];
        mx = fmaxf(mx, y[j]);
    }
    float sum = 0.f;
#pragma unroll
    for (int j = 0; j < 10; ++j) { y[j] = expf(y[j] - mx); sum += y[j]; }
    float inv = 1.f / sum;
#pragma unroll
    for (int j = 0; j < 10; ++j) out[b * 10 + j] = y[j] * inv;
}

extern "C" void kernel_launch(void* const* d_in, const int* in_sizes, int n_in,
                              void* d_out, int out_size, void* d_ws, size_t ws_size,
                              hipStream_t stream)
{
    const float* inp = (const float*)d_in[0];
    const float* w1  = (const float*)d_in[1];
    const float* w2  = (const float*)d_in[2];
    const float* w3  = (const float*)d_in[3];
    const float* d1w = (const float*)d_in[4];
    const float* d2w = (const float*)d_in[5];
    const float* m1 = (const float*)d_in[6],  *v1 = (const float*)d_in[7],  *be1 = (const float*)d_in[8];
    const float* m2 = (const float*)d_in[9],  *v2 = (const float*)d_in[10], *be2 = (const float*)d_in[11];
    const float* m3 = (const float*)d_in[12], *v3 = (const float*)d_in[13], *be3 = (const float*)d_in[14];
    const float* m4 = (const float*)d_in[15], *v4 = (const float*)d_in[16], *be4 = (const float*)d_in[17];
    const float* m5 = (const float*)d_in[18], *v5 = (const float*)d_in[19], *be5 = (const float*)d_in[20];

    char* ws = (char*)d_ws;
    u32* bits1 = (u32*)(ws + OFF_BITS1);
    u64* bits2 = (u64*)(ws + OFF_BITS2);
    u64* bits3 = (u64*)(ws + OFF_BITS3);
    u64* bitsD = (u64*)(ws + OFF_BITSD);
    u32* w2b   = (u32*)(ws + OFF_W2B);
    u64* w3b   = (u64*)(ws + OFF_W3B);
    u64* d1wb  = (u64*)(ws + OFF_D1WB);
    u64* d2wb  = (u64*)(ws + OFF_D2WB);
    float* t1  = (float*)(ws + OFF_T1);
    float* t2  = (float*)(ws + OFF_T2);
    float* t3  = (float*)(ws + OFF_T3);
    float* t4  = (float*)(ws + OFF_T4);

    k_prep  <<<43,    256, 0, stream>>>(w2, w3, d1w, d2w,
                                        m1, v1, be1, m2, v2, be2,
                                        m3, v3, be3, m4, v4, be4,
                                        w2b, w3b, d1wb, d2wb, t1, t2, t3, t4);
    k_conv1 <<<961,   256, 0, stream>>>(inp, w1, t1, bits1);
    k_conv2 <<<12544, 256, 0, stream>>>(bits1, w2b, t2, bits2);
    k_conv3 <<<9216,  256, 0, stream>>>(bits2, w3b, t3, bits3);
    k_dense1<<<64,    256, 0, stream>>>(bits3, d1wb, t4, bitsD);
    k_dense2<<<1,     256, 0, stream>>>(bitsD, d2wb, m5, v5, be5, (float*)d_out);
}

// Round 7
// 146.612 us; speedup vs baseline: 1.1503x; 1.1503x over previous
//
#include <hip/hip_runtime.h>

typedef unsigned int u32;
typedef unsigned long long u64;

#define BN_EPS 1e-3f

// ---------------- workspace layout (bytes) ----------------
// bits1: [256][31][31] u32   conv1->pool->bn1->sign
// bits2: [256][14][14] u64   conv2->pool->bn2->sign
// w2b  : [9][64]  u32        sign bits of w2 over ic (32)
// w3b  : [9][64]  u64        sign bits of w3 over ic (64)
// d1wb : [144][64] u64       sign bits of d1w rows (bit j = row w*64+j), col oc
// d2wb : [10] u64            sign bits of d2w rows
// t2..t4: per-channel sign thresholds  t = mean - beta*sqrt(var+eps)
static const size_t OFF_BITS1 = 0;            // 984064
static const size_t OFF_BITS2 = 984064;       // 401408
static const size_t OFF_W2B   = 1682432;      // 2304
static const size_t OFF_W3B   = 1684736;      // 4608
static const size_t OFF_D1WB  = 1689344;      // 73728
static const size_t OFF_D2WB  = 1763072;      // 128
static const size_t OFF_T2    = 1763328;      // 256
static const size_t OFF_T3    = 1763584;      // 256
static const size_t OFF_T4    = 1763840;      // 256
// total ~1.77 MB

// ---------------- head: conv1 (blocks 0..960) + weight-pack prep (961..1003) --
// conv1: thread = one pooled pixel (b,ph,pw); produces one u32 (32 channels).
// conv1 blocks compute their own t1 thresholds (32 sqrt — free), so prep
// blocks have NO consumer inside this kernel (no inter-block dependency).
__global__ __launch_bounds__(256) void k_head(
    const float* __restrict__ inp, const float* __restrict__ w1,
    const float* __restrict__ m1, const float* __restrict__ v1, const float* __restrict__ be1,
    const float* __restrict__ w2, const float* __restrict__ w3,
    const float* __restrict__ d1w, const float* __restrict__ d2w,
    const float* __restrict__ m2, const float* __restrict__ v2, const float* __restrict__ be2,
    const float* __restrict__ m3, const float* __restrict__ v3, const float* __restrict__ be3,
    const float* __restrict__ m4, const float* __restrict__ v4, const float* __restrict__ be4,
    u32* __restrict__ bits1,
    u32* __restrict__ w2b, u64* __restrict__ w3b, u64* __restrict__ d1wb,
    u64* __restrict__ d2wb, float* __restrict__ t2, float* __restrict__ t3,
    float* __restrict__ t4)
{
    int tid = threadIdx.x;

    if (blockIdx.x >= 961) {             // ---- prep path ----
        int pb = blockIdx.x - 961;
        if (pb < 36) {                   // d1w: 9216 words, [wi][oc]
            int idx = pb * 256 + tid;    // wi = idx>>6, oc = idx&63
            int wi = idx >> 6, oc = idx & 63;
            u64 bits = 0;
            for (int j = 0; j < 64; ++j)
                bits |= (u64)(d1w[(wi * 64 + j) * 64 + oc] >= 0.f) << j;
            d1wb[idx] = bits;
        } else if (pb < 39) {            // w2: 576 words [tap][oc]
            int idx = (pb - 36) * 256 + tid;
            if (idx < 576) {
                int tap = idx >> 6, oc = idx & 63;
                u32 bits = 0;
                for (int ic = 0; ic < 32; ++ic)
                    bits |= (u32)(w2[(tap * 32 + ic) * 64 + oc] >= 0.f) << ic;
                w2b[idx] = bits;
            }
        } else if (pb < 42) {            // w3: 576 words [tap][oc]
            int idx = (pb - 39) * 256 + tid;
            if (idx < 576) {
                int tap = idx >> 6, oc = idx & 63;
                u64 bits = 0;
                for (int ic = 0; ic < 64; ++ic)
                    bits |= (u64)(w3[(tap * 64 + ic) * 64 + oc] >= 0.f) << ic;
                w3b[idx] = bits;
            }
        } else {                         // thresholds + d2w pack
            if (tid < 64)        t2[tid] = m2[tid] - be2[tid] * sqrtf(v2[tid] + BN_EPS);
            else if (tid < 128) { int c = tid - 64;  t3[c] = m3[c] - be3[c] * sqrtf(v3[c] + BN_EPS); }
            else if (tid < 192) { int c = tid - 128; t4[c] = m4[c] - be4[c] * sqrtf(v4[c] + BN_EPS); }
            else if (tid < 202) {
                int oc = tid - 192;      // d2w: [64][10]
                u64 bits = 0;
                for (int j = 0; j < 64; ++j)
                    bits |= (u64)(d2w[j * 10 + oc] >= 0.f) << j;
                d2wb[oc] = bits;
            }
        }
        return;
    }

    // ---- conv1 path ----
    __shared__ float wf[32 * 28];   // [oc][tap], padded 27->28 (float4-aligned rows)
    __shared__ float t1s[32];
    for (int i = tid; i < 864; i += 256) {
        int oc = i / 27, tap = i - oc * 27;
        wf[oc * 28 + tap] = (w1[tap * 32 + oc] >= 0.f) ? 1.f : -1.f;
    }
    if (tid < 32) t1s[tid] = m1[tid] - be1[tid] * sqrtf(v1[tid] + BN_EPS);
    __syncthreads();

    int gid = blockIdx.x * 256 + tid;        // < 246016 = 256*961
    int b = gid / 961;
    int p = gid - b * 961;
    int ph = p / 31, pw = p - ph * 31;

    // 4x4x3 input patch covering the 2x2 conv positions
    float x[4][4][3];
    const float* base = inp + ((b * 64 + 2 * ph) * 64 + 2 * pw) * 3;
#pragma unroll
    for (int i = 0; i < 4; ++i)
#pragma unroll
        for (int j = 0; j < 4; ++j)
#pragma unroll
            for (int k = 0; k < 3; ++k)
                x[i][j][k] = base[(i * 64 + j) * 3 + k];

    u32 word = 0;
#pragma unroll 1
    for (int oc = 0; oc < 32; ++oc) {
        float wv[28];
        const float4* wq = reinterpret_cast<const float4*>(wf + oc * 28);
#pragma unroll
        for (int q = 0; q < 7; ++q) {
            float4 t = wq[q];
            wv[4 * q] = t.x; wv[4 * q + 1] = t.y; wv[4 * q + 2] = t.z; wv[4 * q + 3] = t.w;
        }
        float s00 = 0.f, s01 = 0.f, s10 = 0.f, s11 = 0.f;
#pragma unroll
        for (int ky = 0; ky < 3; ++ky)
#pragma unroll
            for (int kx = 0; kx < 3; ++kx)
#pragma unroll
                for (int ic = 0; ic < 3; ++ic) {
                    float w = wv[(ky * 3 + kx) * 3 + ic];
                    s00 = fmaf(w, x[ky][kx][ic], s00);
                    s01 = fmaf(w, x[ky][kx + 1][ic], s01);
                    s10 = fmaf(w, x[ky + 1][kx][ic], s10);
                    s11 = fmaf(w, x[ky + 1][kx + 1][ic], s11);
                }
        float m = fmaxf(fmaxf(s00, s01), fmaxf(s10, s11));
        if (m >= t1s[oc]) word |= (1u << oc);
    }
    bits1[gid] = word;
}

// ---------------- conv2 (XNOR) + maxpool + bn2-sign ----------------
// wave = one pooled pixel, lane = oc (64). ballot -> u64 word.
__global__ __launch_bounds__(256) void k_conv2(
    const u32* __restrict__ bits1, const u32* __restrict__ w2b,
    const float* __restrict__ t2, u64* __restrict__ bits2)
{
    int lane = threadIdx.x & 63;
    int wid = blockIdx.x * 4 + (threadIdx.x >> 6);   // < 50176 = 256*196
    int b = wid / 196;
    int p = wid - b * 196;
    int ph = p / 14, pw = p - ph * 14;

    const u32* xb = bits1 + b * 961 + (2 * ph) * 31 + 2 * pw;
    u32 xw[4][4];
#pragma unroll
    for (int i = 0; i < 4; ++i)
#pragma unroll
        for (int j = 0; j < 4; ++j)
            xw[i][j] = xb[i * 31 + j];

    u32 wv[9];
#pragma unroll
    for (int t = 0; t < 9; ++t) wv[t] = w2b[t * 64 + lane];

    int mn = 1 << 30;
#pragma unroll
    for (int dy = 0; dy < 2; ++dy)
#pragma unroll
        for (int dx = 0; dx < 2; ++dx) {
            int s = 0;
#pragma unroll
            for (int ky = 0; ky < 3; ++ky)
#pragma unroll
                for (int kx = 0; kx < 3; ++kx)
                    s += __popc(xw[dy + ky][dx + kx] ^ wv[ky * 3 + kx]);
            mn = min(mn, s);
        }
    float val = (float)(288 - 2 * mn);      // max over pool = min popcount
    u64 word = __ballot(val >= t2[lane]);
    if (lane == 0) bits2[wid] = word;
}

// ---------------- tail: conv3 + bn3-sign + dense1 + bn4-sign + dense2 + softmax
// one block per image (256 threads = 4 waves). All deps are intra-image.
__global__ __launch_bounds__(256) void k_tail(
    const u64* __restrict__ bits2, const u64* __restrict__ w3b,
    const float* __restrict__ t3, const u64* __restrict__ d1wb,
    const float* __restrict__ t4, const u64* __restrict__ d2wb,
    const float* __restrict__ m5, const float* __restrict__ v5,
    const float* __restrict__ be5, float* __restrict__ out)
{
    __shared__ u64 sb3[144];        // conv3 output bits, word=(h*12+w), bit=ic
    __shared__ int part[4][64];     // dense1 partial popcounts [quarter][oc]

    int tid  = threadIdx.x;
    int lane = tid & 63;
    int wv_  = tid >> 6;            // wave id 0..3
    int b    = blockIdx.x;

    // ---- conv3: each wave handles 36 of the 144 output positions ----
    u64 wreg[9];
#pragma unroll
    for (int t = 0; t < 9; ++t) wreg[t] = w3b[t * 64 + lane];
    float t3v = t3[lane];

    const u64* ib = bits2 + b * 196;
#pragma unroll 2
    for (int i = 0; i < 36; ++i) {
        int pos = wv_ * 36 + i;
        int h = pos / 12, w = pos - h * 12;
        const u64* xb = ib + h * 14 + w;
        int s = 0;
#pragma unroll
        for (int ky = 0; ky < 3; ++ky)
#pragma unroll
            for (int kx = 0; kx < 3; ++kx)
                s += __popcll(xb[ky * 14 + kx] ^ wreg[ky * 3 + kx]);
        u64 word = __ballot((float)(576 - 2 * s) >= t3v);
        if (lane == 0) sb3[pos] = word;
    }
    __syncthreads();

    // ---- dense1: thread (q,oc) sums 36 of 144 words ----
    {
        int q = wv_, oc = lane;
        int s = 0;
#pragma unroll 6
        for (int i = 0; i < 36; ++i) {
            int w = q * 36 + i;
            s += __popcll(sb3[w] ^ d1wb[w * 64 + oc]);
        }
        part[q][oc] = s;
    }
    __syncthreads();

    // ---- bn4-sign + dense2 + bn5 + softmax: wave 0 only ----
    if (tid < 64) {
        int s = part[0][tid] + part[1][tid] + part[2][tid] + part[3][tid];
        float val = (float)(9216 - 2 * s);
        u64 xv = __ballot(val >= t4[tid]);   // bit oc of dense1 sign output
        if (tid < 16) {
            int j = tid;
            bool ok = j < 10;
            float y = -1e30f;
            if (ok) {
                int v = 64 - 2 * (int)__popcll(xv ^ d2wb[j]);
                y = ((float)v - m5[j]) * rsqrtf(v5[j] + BN_EPS) + be5[j];
            }
            float mx = y;
#pragma unroll
            for (int off = 8; off >= 1; off >>= 1)
                mx = fmaxf(mx, __shfl_xor(mx, off, 16));
            float e = ok ? expf(y - mx) : 0.f;
            float sum = e;
#pragma unroll
            for (int off = 8; off >= 1; off >>= 1)
                sum += __shfl_xor(sum, off, 16);
            if (ok) out[b * 10 + j] = e / sum;
        }
    }
}

extern "C" void kernel_launch(void* const* d_in, const int* in_sizes, int n_in,
                              void* d_out, int out_size, void* d_ws, size_t ws_size,
                              hipStream_t stream)
{
    const float* inp = (const float*)d_in[0];
    const float* w1  = (const float*)d_in[1];
    const float* w2  = (const float*)d_in[2];
    const float* w3  = (const float*)d_in[3];
    const float* d1w = (const float*)d_in[4];
    const float* d2w = (const float*)d_in[5];
    const float* m1 = (const float*)d_in[6],  *v1 = (const float*)d_in[7],  *be1 = (const float*)d_in[8];
    const float* m2 = (const float*)d_in[9],  *v2 = (const float*)d_in[10], *be2 = (const float*)d_in[11];
    const float* m3 = (const float*)d_in[12], *v3 = (const float*)d_in[13], *be3 = (const float*)d_in[14];
    const float* m4 = (const float*)d_in[15], *v4 = (const float*)d_in[16], *be4 = (const float*)d_in[17];
    const float* m5 = (const float*)d_in[18], *v5 = (const float*)d_in[19], *be5 = (const float*)d_in[20];

    char* ws = (char*)d_ws;
    u32* bits1 = (u32*)(ws + OFF_BITS1);
    u64* bits2 = (u64*)(ws + OFF_BITS2);
    u32* w2b   = (u32*)(ws + OFF_W2B);
    u64* w3b   = (u64*)(ws + OFF_W3B);
    u64* d1wb  = (u64*)(ws + OFF_D1WB);
    u64* d2wb  = (u64*)(ws + OFF_D2WB);
    float* t2  = (float*)(ws + OFF_T2);
    float* t3  = (float*)(ws + OFF_T3);
    float* t4  = (float*)(ws + OFF_T4);

    k_head <<<1004,  256, 0, stream>>>(inp, w1, m1, v1, be1,
                                       w2, w3, d1w, d2w,
                                       m2, v2, be2, m3, v3, be3, m4, v4, be4,
                                       bits1, w2b, w3b, d1wb, d2wb, t2, t3, t4);
    k_conv2<<<12544, 256, 0, stream>>>(bits1, w2b, t2, bits2);
    k_tail <<<256,   256, 0, stream>>>(bits2, w3b, t3, d1wb, t4, d2wb,
                                       m5, v5, be5, (float*)d_out);
}